// Round 5
// baseline (119.667 us; speedup 1.0000x reference)
//
#include <hip/hip_runtime.h>

// Problem constants (fixed by the reference)
#define N_ATOMS   8388608
#define N_MOLS    65536
#define APM       128            // atoms per molecule (contiguous segments)

#define BLOCK_THREADS 256
#define GRID_BLOCKS   (N_MOLS / 2 / (BLOCK_THREADS / 64))   // 8192: one mol-pair per wave

// Weights folded with normalizations:
//   loss = 1*e_term + 100*f_term + 10*im_term
//   e_term  = (1/N_MOLS)       * sum_m ((re-pe)/128)^2
//   f_term  = (1/(3*N_ATOMS))  * sum   d^2
//   im_term = (1/(3*N_MOLS))   * sum_m (dx^2+dy^2+dz^2)
__device__ __constant__ float kWF  = 100.0f / (3.0f * (float)N_ATOMS);
__device__ __constant__ float kWIM = 10.0f  / (3.0f * (float)N_MOLS);
__device__ __constant__ float kWE  = 1.0f   / (float)N_MOLS;
#define INV_APM (1.0f / 128.0f)

__global__ __launch_bounds__(BLOCK_THREADS) void wef_loss_kernel(
    const float* __restrict__ ref_e,
    const float* __restrict__ pred_e,
    const float* __restrict__ ref_f,
    const float* __restrict__ pred_f,
    float* __restrict__ out)
{
    const int tid  = blockIdx.x * BLOCK_THREADS + threadIdx.x;
    const int lane = threadIdx.x & 63;
    const int half = lane >> 5;        // which molecule of the wave's pair
    const int t    = lane & 31;        // lane within molecule group
    const int wave = tid >> 6;         // global wave id, 0..32767: ONE pair, no loop

    float p = 0.0f;                    // weighted partial loss for this thread

    // Energy term: one thread per molecule, coalesced (first 65536 threads).
    if (tid < N_MOLS) {
        float de = (ref_e[tid] - pred_e[tid]) * INV_APM;
        p = de * de * kWE;
    }

    const float4* __restrict__ rf4 = (const float4*)ref_f;
    const float4* __restrict__ pf4 = (const float4*)pred_f;
    const int tm3 = t % 3;             // component rotation seed for this lane

    const int m    = 2 * wave + half;
    const int base = m * 96 + t;       // molecule start in float4 units, + lane

    float sx = 0.f, sy = 0.f, sz = 0.f, ssq = 0.f;

    #pragma unroll
    for (int k = 0; k < 3; ++k) {
        const int q = base + 32 * k;   // 32 lanes -> 512B contiguous
        float4 rv = rf4[q];
        float4 pv = pf4[q];
        float dx = pv.x - rv.x;
        float dy = pv.y - rv.y;
        float dz = pv.z - rv.z;
        float dw = pv.w - rv.w;
        ssq += dx*dx + dy*dy + dz*dz + dw*dw;

        // flat components of this float4: (r, r+1, r+2, r) mod 3, r = q % 3
        int rk = tm3 + 2 * k;          // (t + 32k) % 3 == (t + 2k) % 3
        rk = (rk >= 3) ? rk - 3 : rk;
        rk = (rk >= 3) ? rk - 3 : rk;
        float a = dx + dw;   // component r
        float b = dy;        // component (r+1)%3
        float c = dz;        // component (r+2)%3
        sx += (rk == 0) ? a : ((rk == 1) ? c : b);
        sy += (rk == 0) ? b : ((rk == 1) ? a : c);
        sz += (rk == 0) ? c : ((rk == 1) ? b : a);
    }

    p += ssq * kWF;

    // reduce molecule force-sum over the 32-lane group
    #pragma unroll
    for (int off = 16; off >= 1; off >>= 1) {
        sx += __shfl_xor(sx, off);
        sy += __shfl_xor(sy, off);
        sz += __shfl_xor(sz, off);
    }

    if (t == 0) {
        p += (sx*sx + sy*sy + sz*sz) * kWIM;
    }

    // full-wave reduction of the weighted partial
    #pragma unroll
    for (int off = 32; off >= 1; off >>= 1) p += __shfl_xor(p, off);

    __shared__ float ws[BLOCK_THREADS / 64];
    const int waveInBlock = threadIdx.x >> 6;
    if (lane == 0) ws[waveInBlock] = p;
    __syncthreads();
    if (threadIdx.x == 0) {
        float s = 0.f;
        #pragma unroll
        for (int i = 0; i < BLOCK_THREADS / 64; ++i) s += ws[i];
        atomicAdd(out, s);
    }
}

extern "C" void kernel_launch(void* const* d_in, const int* in_sizes, int n_in,
                              void* d_out, int out_size, void* d_ws, size_t ws_size,
                              hipStream_t stream) {
    const float* ref_e  = (const float*)d_in[0];
    const float* pred_e = (const float*)d_in[1];
    const float* ref_f  = (const float*)d_in[2];
    const float* pred_f = (const float*)d_in[3];
    // d_in[4] = segment_ids: structurally repeat(arange(N_MOLS), 128) -> not needed.

    float* out = (float*)d_out;

    // Harness poisons d_out once and never re-poisons between replays; we
    // accumulate with atomics, so zero it every launch (graph-capture safe).
    hipMemsetAsync(out, 0, sizeof(float), stream);

    wef_loss_kernel<<<dim3(GRID_BLOCKS), dim3(BLOCK_THREADS), 0, stream>>>(
        ref_e, pred_e, ref_f, pred_f, out);
}

// Round 6
// 36.506 us; speedup vs baseline: 3.2780x; 3.2780x over previous
//
#include <hip/hip_runtime.h>

// Problem constants (fixed by the reference)
#define N_ATOMS   8388608
#define N_MOLS    65536
#define APM       128            // atoms per molecule (contiguous segments)

#define GRID_BLOCKS 2048
#define BLOCK_THREADS 256
#define TOTAL_WAVES (GRID_BLOCKS * BLOCK_THREADS / 64)      // 8192
#define N_ITERS (N_MOLS / 2 / TOTAL_WAVES)                  // 4

// Weights folded with normalizations:
//   loss = 1*e_term + 100*f_term + 10*im_term
//   e_term  = (1/N_MOLS)       * sum_m ((re-pe)/128)^2
//   f_term  = (1/(3*N_ATOMS))  * sum   d^2
//   im_term = (1/(3*N_MOLS))   * sum_m (dx^2+dy^2+dz^2)
__device__ __constant__ float kWF  = 100.0f / (3.0f * (float)N_ATOMS);
__device__ __constant__ float kWIM = 10.0f  / (3.0f * (float)N_MOLS);
__device__ __constant__ float kWE  = 1.0f   / (float)N_MOLS;
#define INV_APM (1.0f / 128.0f)

__global__ __launch_bounds__(BLOCK_THREADS) void wef_loss_stage1(
    const float* __restrict__ ref_e,
    const float* __restrict__ pred_e,
    const float* __restrict__ ref_f,
    const float* __restrict__ pred_f,
    float* __restrict__ partials)   // one slot per block -> NO atomic contention
{
    const int tid  = blockIdx.x * BLOCK_THREADS + threadIdx.x;
    const int lane = threadIdx.x & 63;
    const int half = lane >> 5;        // which molecule of the wave's pair
    const int t    = lane & 31;        // lane within molecule group
    const int wave = tid >> 6;         // global wave id, 0..8191

    float p = 0.0f;                    // weighted partial loss for this thread

    // Energy term: one thread per molecule, coalesced (first 65536 threads).
    if (tid < N_MOLS) {
        float de = (ref_e[tid] - pred_e[tid]) * INV_APM;
        p = de * de * kWE;
    }

    const float4* __restrict__ rf4 = (const float4*)ref_f;
    const float4* __restrict__ pf4 = (const float4*)pred_f;
    const int tm3 = t % 3;             // component rotation seed for this lane

    #pragma unroll
    for (int it = 0; it < N_ITERS; ++it) {
        const int wi = wave + it * TOTAL_WAVES;
        const int m  = 2 * wi + half;
        const int base = m * 96;       // molecule start, in float4 units

        float sx = 0.f, sy = 0.f, sz = 0.f, ssq = 0.f;

        #pragma unroll
        for (int k = 0; k < 3; ++k) {
            const int q = base + t + 32 * k;  // 32 lanes -> 512B contiguous
            float4 rv = rf4[q];
            float4 pv = pf4[q];
            float dx = pv.x - rv.x;
            float dy = pv.y - rv.y;
            float dz = pv.z - rv.z;
            float dw = pv.w - rv.w;
            ssq += dx*dx + dy*dy + dz*dz + dw*dw;

            // flat components of this float4: (r, r+1, r+2, r) mod 3, r = q % 3
            int rk = tm3 + 2 * k;              // (t + 32k) % 3 == (t + 2k) % 3
            rk = (rk >= 3) ? rk - 3 : rk;
            rk = (rk >= 3) ? rk - 3 : rk;
            float a = dx + dw;   // component r
            float b = dy;        // component (r+1)%3
            float c = dz;        // component (r+2)%3
            sx += (rk == 0) ? a : ((rk == 1) ? c : b);
            sy += (rk == 0) ? b : ((rk == 1) ? a : c);
            sz += (rk == 0) ? c : ((rk == 1) ? b : a);
        }

        p += ssq * kWF;

        // reduce molecule force-sum over the 32-lane group
        #pragma unroll
        for (int off = 16; off >= 1; off >>= 1) {
            sx += __shfl_xor(sx, off);
            sy += __shfl_xor(sy, off);
            sz += __shfl_xor(sz, off);
        }

        if (t == 0) {
            p += (sx*sx + sy*sy + sz*sz) * kWIM;
        }
    }

    // full-wave reduction of the weighted partial
    #pragma unroll
    for (int off = 32; off >= 1; off >>= 1) p += __shfl_xor(p, off);

    __shared__ float ws[BLOCK_THREADS / 64];
    const int waveInBlock = threadIdx.x >> 6;
    if (lane == 0) ws[waveInBlock] = p;
    __syncthreads();
    if (threadIdx.x == 0) {
        float s = 0.f;
        #pragma unroll
        for (int i = 0; i < BLOCK_THREADS / 64; ++i) s += ws[i];
        partials[blockIdx.x] = s;      // plain store, distinct address per block
    }
}

// Stage 2: reduce GRID_BLOCKS partials (8 KB, L2-resident) -> scalar out.
__global__ __launch_bounds__(256) void wef_loss_stage2(
    const float* __restrict__ partials,
    float* __restrict__ out)
{
    float s = 0.f;
    #pragma unroll
    for (int i = 0; i < GRID_BLOCKS / 256; ++i)
        s += partials[threadIdx.x + i * 256];

    #pragma unroll
    for (int off = 32; off >= 1; off >>= 1) s += __shfl_xor(s, off);

    __shared__ float ws[4];
    const int wib = threadIdx.x >> 6;
    if ((threadIdx.x & 63) == 0) ws[wib] = s;
    __syncthreads();
    if (threadIdx.x == 0) out[0] = ws[0] + ws[1] + ws[2] + ws[3];
}

extern "C" void kernel_launch(void* const* d_in, const int* in_sizes, int n_in,
                              void* d_out, int out_size, void* d_ws, size_t ws_size,
                              hipStream_t stream) {
    const float* ref_e  = (const float*)d_in[0];
    const float* pred_e = (const float*)d_in[1];
    const float* ref_f  = (const float*)d_in[2];
    const float* pred_f = (const float*)d_in[3];
    // d_in[4] = segment_ids: structurally repeat(arange(N_MOLS), 128) -> not needed.

    float* out      = (float*)d_out;
    float* partials = (float*)d_ws;    // 2048 floats = 8 KB scratch

    wef_loss_stage1<<<dim3(GRID_BLOCKS), dim3(BLOCK_THREADS), 0, stream>>>(
        ref_e, pred_e, ref_f, pred_f, partials);
    wef_loss_stage2<<<dim3(1), dim3(256), 0, stream>>>(partials, out);
}